// Round 1
// baseline (874.551 us; speedup 1.0000x reference)
//
#include <hip/hip_runtime.h>

#define N_NODES 50000
#define N_EDGES 800000
#define IN_CH   256
#define HID     32
#define HEADS1  4
#define C1      128      // HEADS1*HID
#define OUT_CH  64
#define NEG     0.2f

// ---- monotone float<->uint encoding for atomicMax on floats ----
__device__ __forceinline__ unsigned enc_f(float f) {
    unsigned u = __float_as_uint(f);
    return (u & 0x80000000u) ? ~u : (u | 0x80000000u);
}
__device__ __forceinline__ float dec_f(unsigned e) {
    unsigned u = (e & 0x80000000u) ? (e ^ 0x80000000u) : ~e;
    return __uint_as_float(u);
}

// ---- simple register-tiled fp32 GEMM: C[M,NCOL] = A[M,KTOT] @ B[KTOT,NCOL] ----
// 256 threads, tile = 64 rows x NCOL cols; thread computes 4 rows x (NCOL/16) cols.
template<int KTOT, int NCOL>
__global__ __launch_bounds__(256) void gat_gemm(const float* __restrict__ A,
                                                const float* __restrict__ B,
                                                float* __restrict__ C, int M) {
    constexpr int TN  = NCOL / 16;
    constexpr int LDA = 68;        // As[k][row], padded
    constexpr int LDB = NCOL + 4;  // Bs[k][col], padded
    __shared__ float As[32 * LDA];
    __shared__ float Bs[32 * LDB];
    const int tid = threadIdx.x;
    const int ty = tid >> 4, tx = tid & 15;
    const int row0 = blockIdx.x * 64;
    const int r0 = ty * 4;
    const int c0 = tx * TN;
    float acc[4][TN];
#pragma unroll
    for (int r = 0; r < 4; ++r)
#pragma unroll
        for (int j = 0; j < TN; ++j) acc[r][j] = 0.f;

    for (int kk = 0; kk < KTOT; kk += 32) {
        // stage A (64x32), transposed into As[k][row]
#pragma unroll
        for (int p = 0; p < 2; ++p) {
            int r  = (tid >> 3) + p * 32;
            int kb = (tid & 7) * 4;
            float4 v = make_float4(0.f, 0.f, 0.f, 0.f);
            int gr = row0 + r;
            if (gr < M) v = *(const float4*)(A + (size_t)gr * KTOT + kk + kb);
            As[(kb + 0) * LDA + r] = v.x;
            As[(kb + 1) * LDA + r] = v.y;
            As[(kb + 2) * LDA + r] = v.z;
            As[(kb + 3) * LDA + r] = v.w;
        }
        // stage B (32xNCOL)
        constexpr int NV = NCOL / 4;
        constexpr int NLOAD = 32 * NV / 256;
#pragma unroll
        for (int p = 0; p < NLOAD; ++p) {
            int idx = tid + p * 256;
            int k = idx / NV;
            int j = (idx % NV) * 4;
            *(float4*)(&Bs[k * LDB + j]) = *(const float4*)(B + (size_t)(kk + k) * NCOL + j);
        }
        __syncthreads();
#pragma unroll
        for (int k = 0; k < 32; ++k) {
            float4 a = *(const float4*)(&As[k * LDA + r0]);
            float av[4] = {a.x, a.y, a.z, a.w};
            float bv[TN];
#pragma unroll
            for (int j = 0; j < TN; j += 4) {
                float4 b = *(const float4*)(&Bs[k * LDB + c0 + j]);
                bv[j] = b.x; bv[j + 1] = b.y; bv[j + 2] = b.z; bv[j + 3] = b.w;
            }
#pragma unroll
            for (int r = 0; r < 4; ++r)
#pragma unroll
                for (int j = 0; j < TN; ++j)
                    acc[r][j] = fmaf(av[r], bv[j], acc[r][j]);
        }
        __syncthreads();
    }
#pragma unroll
    for (int r = 0; r < 4; ++r) {
        int gr = row0 + r0 + r;
        if (gr < M) {
#pragma unroll
            for (int j = 0; j < TN; j += 4)
                *(float4*)(C + (size_t)gr * NCOL + c0 + j) =
                    make_float4(acc[r][j], acc[r][j + 1], acc[r][j + 2], acc[r][j + 3]);
        }
    }
}

// ---- layer1 attention coefficients: as/ad [N,4] ----
__global__ void gat_coef1(const float* __restrict__ h1, const float* __restrict__ a_s,
                          const float* __restrict__ a_d, float* __restrict__ as_n,
                          float* __restrict__ ad_n) {
    int t = blockIdx.x * blockDim.x + threadIdx.x;
    if (t >= N_NODES * HEADS1) return;
    int n = t >> 2, h = t & 3;
    const float* hp = h1 + (size_t)n * C1 + h * HID;
    const float* ap = a_s + h * HID;
    const float* dp = a_d + h * HID;
    float s = 0.f, d = 0.f;
#pragma unroll
    for (int c = 0; c < HID; ++c) {
        float v = hp[c];
        s = fmaf(v, ap[c], s);
        d = fmaf(v, dp[c], d);
    }
    as_n[t] = s;
    ad_n[t] = d;
}

// ---- layer1 segment max over dst (per head) ----
__global__ void gat_max1(const int* __restrict__ src, const int* __restrict__ dst,
                         const float* __restrict__ as_n, const float* __restrict__ ad_n,
                         unsigned* __restrict__ menc) {
    int t = blockIdx.x * blockDim.x + threadIdx.x;
    if (t >= N_EDGES * HEADS1) return;
    int e = t >> 2, h = t & 3;
    int s = src[e], d = dst[e];
    float x = as_n[s * 4 + h] + ad_n[d * 4 + h];
    x = x > 0.f ? x : NEG * x;
    atomicMax(menc + d * 4 + h, enc_f(x));
}

// ---- layer1 fused exp + denom + channel aggregation (unnormalized) ----
__global__ __launch_bounds__(256) void gat_aggr1(const int* __restrict__ src,
                                                 const int* __restrict__ dst,
                                                 const float* __restrict__ as_n,
                                                 const float* __restrict__ ad_n,
                                                 const unsigned* __restrict__ menc,
                                                 const float* __restrict__ h1,
                                                 float* __restrict__ outacc,
                                                 float* __restrict__ denom) {
    const int c = threadIdx.x & 127;
    const int slot = threadIdx.x >> 7;
    const int h = c >> 5;
    for (int e = blockIdx.x * 2 + slot; e < N_EDGES; e += gridDim.x * 2) {
        int s = src[e], d = dst[e];
        float x = as_n[s * 4 + h] + ad_n[d * 4 + h];
        x = x > 0.f ? x : NEG * x;
        float m = dec_f(menc[d * 4 + h]);
        float ex = __expf(x - m);
        if ((c & 31) == 0) atomicAdd(denom + d * 4 + h, ex);
        float v = h1[(size_t)s * C1 + c] * ex;
        atomicAdd(outacc + (size_t)d * C1 + c, v);
    }
}

// ---- layer1 normalize + bias + relu (in place) ----
__global__ void gat_norm1(float* __restrict__ io, const float* __restrict__ denom,
                          const float* __restrict__ b1) {
    int t = blockIdx.x * blockDim.x + threadIdx.x;
    if (t >= N_NODES * C1) return;
    int n = t >> 7, c = t & 127, h = c >> 5;
    float v = io[t] / (denom[n * 4 + h] + 1e-16f) + b1[c];
    io[t] = v > 0.f ? v : 0.f;
}

// ---- layer2 attention coefficients (1 head, 64 ch): warp per node ----
__global__ void gat_coef2(const float* __restrict__ h2, const float* __restrict__ a_s,
                          const float* __restrict__ a_d, float* __restrict__ as_n,
                          float* __restrict__ ad_n) {
    int warp = (int)((blockIdx.x * blockDim.x + threadIdx.x) >> 6);
    int lane = threadIdx.x & 63;
    if (warp >= N_NODES) return;
    float v = h2[(size_t)warp * 64 + lane];
    float s = v * a_s[lane];
    float d = v * a_d[lane];
#pragma unroll
    for (int o = 32; o > 0; o >>= 1) {
        s += __shfl_down(s, o);
        d += __shfl_down(d, o);
    }
    if (lane == 0) {
        as_n[warp] = s;
        ad_n[warp] = d;
    }
}

__global__ void gat_max2(const int* __restrict__ src, const int* __restrict__ dst,
                         const float* __restrict__ as_n, const float* __restrict__ ad_n,
                         unsigned* __restrict__ menc) {
    int e = blockIdx.x * blockDim.x + threadIdx.x;
    if (e >= N_EDGES) return;
    int s = src[e], d = dst[e];
    float x = as_n[s] + ad_n[d];
    x = x > 0.f ? x : NEG * x;
    atomicMax(menc + d, enc_f(x));
}

__global__ __launch_bounds__(256) void gat_aggr2(const int* __restrict__ src,
                                                 const int* __restrict__ dst,
                                                 const float* __restrict__ as_n,
                                                 const float* __restrict__ ad_n,
                                                 const unsigned* __restrict__ menc,
                                                 const float* __restrict__ h2,
                                                 float* __restrict__ outacc,
                                                 float* __restrict__ denom) {
    const int c = threadIdx.x & 63;
    const int slot = threadIdx.x >> 6;
    for (int e = blockIdx.x * 4 + slot; e < N_EDGES; e += gridDim.x * 4) {
        int s = src[e], d = dst[e];
        float x = as_n[s] + ad_n[d];
        x = x > 0.f ? x : NEG * x;
        float ex = __expf(x - dec_f(menc[d]));
        if (c == 0) atomicAdd(denom + d, ex);
        atomicAdd(outacc + (size_t)d * 64 + c, h2[(size_t)s * 64 + c] * ex);
    }
}

__global__ void gat_final2(float* __restrict__ io, const float* __restrict__ denom,
                           const float* __restrict__ b2) {
    int t = blockIdx.x * blockDim.x + threadIdx.x;
    if (t >= N_NODES * 64) return;
    int n = t >> 6, c = t & 63;
    io[t] = io[t] / (denom[n] + 1e-16f) + b2[c];
}

extern "C" void kernel_launch(void* const* d_in, const int* in_sizes, int n_in,
                              void* d_out, int out_size, void* d_ws, size_t ws_size,
                              hipStream_t stream) {
    const float* x      = (const float*)d_in[0];
    const int*   ei     = (const int*)d_in[1];
    const float* W1     = (const float*)d_in[2];
    const float* a_src1 = (const float*)d_in[3];
    const float* a_dst1 = (const float*)d_in[4];
    const float* b1     = (const float*)d_in[5];
    const float* W2     = (const float*)d_in[6];
    const float* a_src2 = (const float*)d_in[7];
    const float* a_dst2 = (const float*)d_in[8];
    const float* b2     = (const float*)d_in[9];
    float* out = (float*)d_out;

    const int* src = ei;
    const int* dst = ei + N_EDGES;

    // workspace carve-up (256B aligned slices)
    char* w = (char*)d_ws;
    auto carve = [&](size_t bytes) {
        char* p = w;
        w += (bytes + 255) & ~(size_t)255;
        return p;
    };
    float*    h1     = (float*)carve((size_t)N_NODES * C1 * 4);
    float*    as1    = (float*)carve((size_t)N_NODES * 4 * 4);
    float*    ad1    = (float*)carve((size_t)N_NODES * 4 * 4);
    unsigned* menc1  = (unsigned*)carve((size_t)N_NODES * 4 * 4);
    float*    den1   = (float*)carve((size_t)N_NODES * 4 * 4);
    float*    out1   = (float*)carve((size_t)N_NODES * C1 * 4);  // becomes h_relu
    float*    h2     = (float*)carve((size_t)N_NODES * 64 * 4);
    float*    as2    = (float*)carve((size_t)N_NODES * 4);
    float*    ad2    = (float*)carve((size_t)N_NODES * 4);
    unsigned* menc2  = (unsigned*)carve((size_t)N_NODES * 4);
    float*    den2   = (float*)carve((size_t)N_NODES * 4);

    // zero accumulators (enc(−inf)==0, so memset-0 works for menc too)
    hipMemsetAsync(menc1, 0, (size_t)N_NODES * 4 * 4, stream);
    hipMemsetAsync(den1, 0, (size_t)N_NODES * 4 * 4, stream);
    hipMemsetAsync(out1, 0, (size_t)N_NODES * C1 * 4, stream);
    hipMemsetAsync(menc2, 0, (size_t)N_NODES * 4, stream);
    hipMemsetAsync(den2, 0, (size_t)N_NODES * 4, stream);
    hipMemsetAsync(out, 0, (size_t)N_NODES * 64 * 4, stream);

    // ---- layer 1 ----
    gat_gemm<IN_CH, C1><<<(N_NODES + 63) / 64, 256, 0, stream>>>(x, W1, h1, N_NODES);
    gat_coef1<<<(N_NODES * 4 + 255) / 256, 256, 0, stream>>>(h1, a_src1, a_dst1, as1, ad1);
    gat_max1<<<(N_EDGES * 4 + 255) / 256, 256, 0, stream>>>(src, dst, as1, ad1, menc1);
    gat_aggr1<<<16384, 256, 0, stream>>>(src, dst, as1, ad1, menc1, h1, out1, den1);
    gat_norm1<<<(N_NODES * C1 + 255) / 256, 256, 0, stream>>>(out1, den1, b1);

    // ---- layer 2 ----
    gat_gemm<C1, OUT_CH><<<(N_NODES + 63) / 64, 256, 0, stream>>>(out1, W2, h2, N_NODES);
    gat_coef2<<<(N_NODES * 64 + 255) / 256, 256, 0, stream>>>(h2, a_src2, a_dst2, as2, ad2);
    gat_max2<<<(N_EDGES + 255) / 256, 256, 0, stream>>>(src, dst, as2, ad2, menc2);
    gat_aggr2<<<16384, 256, 0, stream>>>(src, dst, as2, ad2, menc2, h2, out, den2);
    gat_final2<<<(N_NODES * 64 + 255) / 256, 256, 0, stream>>>(out, den2, b2);

    (void)in_sizes; (void)n_in; (void)out_size; (void)ws_size;
}

// Round 2
// 398.804 us; speedup vs baseline: 2.1929x; 2.1929x over previous
//
#include <hip/hip_runtime.h>

#define N_NODES 50000
#define N_EDGES 800000
#define IN_CH   256
#define HID     32
#define HEADS1  4
#define C1      128      // HEADS1*HID
#define OUT_CH  64
#define NEG     0.2f
#define NB      ((N_NODES + 255) / 256)   // 196 scan blocks

// ---- simple register-tiled fp32 GEMM: C[M,NCOL] = A[M,KTOT] @ B[KTOT,NCOL] ----
template<int KTOT, int NCOL>
__global__ __launch_bounds__(256) void gat_gemm(const float* __restrict__ A,
                                                const float* __restrict__ B,
                                                float* __restrict__ C, int M) {
    constexpr int TN  = NCOL / 16;
    constexpr int LDA = 68;
    constexpr int LDB = NCOL + 4;
    __shared__ float As[32 * LDA];
    __shared__ float Bs[32 * LDB];
    const int tid = threadIdx.x;
    const int ty = tid >> 4, tx = tid & 15;
    const int row0 = blockIdx.x * 64;
    const int r0 = ty * 4;
    const int c0 = tx * TN;
    float acc[4][TN];
#pragma unroll
    for (int r = 0; r < 4; ++r)
#pragma unroll
        for (int j = 0; j < TN; ++j) acc[r][j] = 0.f;

    for (int kk = 0; kk < KTOT; kk += 32) {
#pragma unroll
        for (int p = 0; p < 2; ++p) {
            int r  = (tid >> 3) + p * 32;
            int kb = (tid & 7) * 4;
            float4 v = make_float4(0.f, 0.f, 0.f, 0.f);
            int gr = row0 + r;
            if (gr < M) v = *(const float4*)(A + (size_t)gr * KTOT + kk + kb);
            As[(kb + 0) * LDA + r] = v.x;
            As[(kb + 1) * LDA + r] = v.y;
            As[(kb + 2) * LDA + r] = v.z;
            As[(kb + 3) * LDA + r] = v.w;
        }
        constexpr int NV = NCOL / 4;
        constexpr int NLOAD = 32 * NV / 256;
#pragma unroll
        for (int p = 0; p < NLOAD; ++p) {
            int idx = tid + p * 256;
            int k = idx / NV;
            int j = (idx % NV) * 4;
            *(float4*)(&Bs[k * LDB + j]) = *(const float4*)(B + (size_t)(kk + k) * NCOL + j);
        }
        __syncthreads();
#pragma unroll
        for (int k = 0; k < 32; ++k) {
            float4 a = *(const float4*)(&As[k * LDA + r0]);
            float av[4] = {a.x, a.y, a.z, a.w};
            float bv[TN];
#pragma unroll
            for (int j = 0; j < TN; j += 4) {
                float4 b = *(const float4*)(&Bs[k * LDB + c0 + j]);
                bv[j] = b.x; bv[j + 1] = b.y; bv[j + 2] = b.z; bv[j + 3] = b.w;
            }
#pragma unroll
            for (int r = 0; r < 4; ++r)
#pragma unroll
                for (int j = 0; j < TN; ++j)
                    acc[r][j] = fmaf(av[r], bv[j], acc[r][j]);
        }
        __syncthreads();
    }
#pragma unroll
    for (int r = 0; r < 4; ++r) {
        int gr = row0 + r0 + r;
        if (gr < M) {
#pragma unroll
            for (int j = 0; j < TN; j += 4)
                *(float4*)(C + (size_t)gr * NCOL + c0 + j) =
                    make_float4(acc[r][j], acc[r][j + 1], acc[r][j + 2], acc[r][j + 3]);
        }
    }
}

// ================= CSR build =================
__global__ void k_deg(const int* __restrict__ dst, int* __restrict__ deg) {
    int e = blockIdx.x * blockDim.x + threadIdx.x;
    if (e < N_EDGES) atomicAdd(deg + dst[e], 1);
}

// block-local exclusive scan; write block totals
__global__ __launch_bounds__(256) void k_scan_block(const int* __restrict__ deg,
                                                    int* __restrict__ offs,
                                                    int* __restrict__ part) {
    __shared__ int s[256];
    int i = blockIdx.x * 256 + threadIdx.x;
    int v = (i < N_NODES) ? deg[i] : 0;
    s[threadIdx.x] = v;
    __syncthreads();
#pragma unroll
    for (int o = 1; o < 256; o <<= 1) {
        int t = (threadIdx.x >= o) ? s[threadIdx.x - o] : 0;
        __syncthreads();
        s[threadIdx.x] += t;
        __syncthreads();
    }
    if (i < N_NODES) offs[i] = s[threadIdx.x] - v;   // exclusive
    if (threadIdx.x == 255) part[blockIdx.x] = s[255];
}

// single-block exclusive scan of NB partials
__global__ __launch_bounds__(256) void k_scan_part(int* __restrict__ part) {
    __shared__ int s[256];
    int v = (threadIdx.x < NB) ? part[threadIdx.x] : 0;
    s[threadIdx.x] = v;
    __syncthreads();
#pragma unroll
    for (int o = 1; o < 256; o <<= 1) {
        int t = (threadIdx.x >= o) ? s[threadIdx.x - o] : 0;
        __syncthreads();
        s[threadIdx.x] += t;
        __syncthreads();
    }
    if (threadIdx.x < NB) part[threadIdx.x] = s[threadIdx.x] - v;
}

__global__ void k_scan_add(int* __restrict__ offs, const int* __restrict__ part,
                           int* __restrict__ cur) {
    int i = blockIdx.x * 256 + threadIdx.x;
    if (i < N_NODES) {
        int o = offs[i] + part[blockIdx.x];
        offs[i] = o;
        cur[i] = o;
    }
}

__global__ void k_scatter(const int* __restrict__ src, const int* __restrict__ dst,
                          int* __restrict__ cur, int* __restrict__ esrc) {
    int e = blockIdx.x * blockDim.x + threadIdx.x;
    if (e < N_EDGES) {
        int pos = atomicAdd(cur + dst[e], 1);
        esrc[pos] = src[e];
    }
}

// ================= attention coefficients =================
__global__ void gat_coef1(const float* __restrict__ h1, const float* __restrict__ a_s,
                          const float* __restrict__ a_d, float* __restrict__ as_n,
                          float* __restrict__ ad_n) {
    int t = blockIdx.x * blockDim.x + threadIdx.x;
    if (t >= N_NODES * HEADS1) return;
    int n = t >> 2, h = t & 3;
    const float* hp = h1 + (size_t)n * C1 + h * HID;
    const float* ap = a_s + h * HID;
    const float* dp = a_d + h * HID;
    float s = 0.f, d = 0.f;
#pragma unroll
    for (int c = 0; c < HID; ++c) {
        float v = hp[c];
        s = fmaf(v, ap[c], s);
        d = fmaf(v, dp[c], d);
    }
    as_n[t] = s;
    ad_n[t] = d;
}

__global__ void gat_coef2(const float* __restrict__ h2, const float* __restrict__ a_s,
                          const float* __restrict__ a_d, float* __restrict__ as_n,
                          float* __restrict__ ad_n) {
    int warp = (int)((blockIdx.x * blockDim.x + threadIdx.x) >> 6);
    int lane = threadIdx.x & 63;
    if (warp >= N_NODES) return;
    float v = h2[(size_t)warp * 64 + lane];
    float s = v * a_s[lane];
    float d = v * a_d[lane];
#pragma unroll
    for (int o = 32; o > 0; o >>= 1) {
        s += __shfl_down(s, o);
        d += __shfl_down(d, o);
    }
    if (lane == 0) {
        as_n[warp] = s;
        ad_n[warp] = d;
    }
}

// ================= CSR aggregation: one wave per dst node =================
// layer1: lane owns channels 2*lane, 2*lane+1; online softmax in registers;
// fused normalize + bias + relu.
__global__ __launch_bounds__(256) void gat_aggr1_csr(const int* __restrict__ offs,
                                                     const int* __restrict__ esrc,
                                                     const float* __restrict__ as1,
                                                     const float* __restrict__ ad1,
                                                     const float* __restrict__ h1,
                                                     const float* __restrict__ b1,
                                                     float* __restrict__ hrelu) {
    int n = blockIdx.x * 4 + (threadIdx.x >> 6);
    if (n >= N_NODES) return;
    int lane = threadIdx.x & 63;
    int c = lane * 2;
    int h = c >> 5;
    int base = offs[n];
    int end = (n == N_NODES - 1) ? N_EDGES : offs[n + 1];
    float ad = ad1[n * 4 + h];
    float m = -INFINITY, den = 0.f, a0 = 0.f, a1 = 0.f;
    for (int i = base; i < end; ++i) {
        int s = esrc[i];
        float x = as1[s * 4 + h] + ad;
        x = x > 0.f ? x : NEG * x;
        if (x > m) {
            float f = __expf(m - x);   // exp(-inf)=0 on first edge
            den *= f; a0 *= f; a1 *= f;
            m = x;
        }
        float ex = __expf(x - m);
        den += ex;
        float2 hv = *(const float2*)(h1 + (size_t)s * C1 + c);
        a0 = fmaf(hv.x, ex, a0);
        a1 = fmaf(hv.y, ex, a1);
    }
    float inv = 1.f / (den + 1e-16f);
    float v0 = a0 * inv + b1[c];
    float v1 = a1 * inv + b1[c + 1];
    v0 = v0 > 0.f ? v0 : 0.f;
    v1 = v1 > 0.f ? v1 : 0.f;
    *(float2*)(hrelu + (size_t)n * C1 + c) = make_float2(v0, v1);
}

// layer2: lane owns 1 channel (64 ch, 1 head); fused bias.
__global__ __launch_bounds__(256) void gat_aggr2_csr(const int* __restrict__ offs,
                                                     const int* __restrict__ esrc,
                                                     const float* __restrict__ as2,
                                                     const float* __restrict__ ad2,
                                                     const float* __restrict__ h2,
                                                     const float* __restrict__ b2,
                                                     float* __restrict__ out) {
    int n = blockIdx.x * 4 + (threadIdx.x >> 6);
    if (n >= N_NODES) return;
    int lane = threadIdx.x & 63;
    int base = offs[n];
    int end = (n == N_NODES - 1) ? N_EDGES : offs[n + 1];
    float ad = ad2[n];
    float m = -INFINITY, den = 0.f, a0 = 0.f;
    for (int i = base; i < end; ++i) {
        int s = esrc[i];
        float x = as2[s] + ad;
        x = x > 0.f ? x : NEG * x;
        if (x > m) {
            float f = __expf(m - x);
            den *= f; a0 *= f;
            m = x;
        }
        float ex = __expf(x - m);
        den += ex;
        a0 = fmaf(h2[(size_t)s * 64 + lane], ex, a0);
    }
    out[(size_t)n * 64 + lane] = a0 / (den + 1e-16f) + b2[lane];
}

extern "C" void kernel_launch(void* const* d_in, const int* in_sizes, int n_in,
                              void* d_out, int out_size, void* d_ws, size_t ws_size,
                              hipStream_t stream) {
    const float* x      = (const float*)d_in[0];
    const int*   ei     = (const int*)d_in[1];
    const float* W1     = (const float*)d_in[2];
    const float* a_src1 = (const float*)d_in[3];
    const float* a_dst1 = (const float*)d_in[4];
    const float* b1     = (const float*)d_in[5];
    const float* W2     = (const float*)d_in[6];
    const float* a_src2 = (const float*)d_in[7];
    const float* a_dst2 = (const float*)d_in[8];
    const float* b2     = (const float*)d_in[9];
    float* out = (float*)d_out;

    const int* src = ei;
    const int* dst = ei + N_EDGES;

    char* w = (char*)d_ws;
    auto carve = [&](size_t bytes) {
        char* p = w;
        w += (bytes + 255) & ~(size_t)255;
        return p;
    };
    float* h1    = (float*)carve((size_t)N_NODES * C1 * 4);
    float* hrelu = (float*)carve((size_t)N_NODES * C1 * 4);
    float* h2    = (float*)carve((size_t)N_NODES * 64 * 4);
    float* as1   = (float*)carve((size_t)N_NODES * 4 * 4);
    float* ad1   = (float*)carve((size_t)N_NODES * 4 * 4);
    float* as2   = (float*)carve((size_t)N_NODES * 4);
    float* ad2   = (float*)carve((size_t)N_NODES * 4);
    int*   deg   = (int*)carve((size_t)N_NODES * 4);
    int*   offs  = (int*)carve((size_t)N_NODES * 4);
    int*   cur   = (int*)carve((size_t)N_NODES * 4);
    int*   part  = (int*)carve((size_t)NB * 4);
    int*   esrc  = (int*)carve((size_t)N_EDGES * 4);

    // ---- CSR build (once, shared by both layers) ----
    hipMemsetAsync(deg, 0, (size_t)N_NODES * 4, stream);
    k_deg<<<(N_EDGES + 255) / 256, 256, 0, stream>>>(dst, deg);
    k_scan_block<<<NB, 256, 0, stream>>>(deg, offs, part);
    k_scan_part<<<1, 256, 0, stream>>>(part);
    k_scan_add<<<NB, 256, 0, stream>>>(offs, part, cur);
    k_scatter<<<(N_EDGES + 255) / 256, 256, 0, stream>>>(src, dst, cur, esrc);

    // ---- layer 1 ----
    gat_gemm<IN_CH, C1><<<(N_NODES + 63) / 64, 256, 0, stream>>>(x, W1, h1, N_NODES);
    gat_coef1<<<(N_NODES * 4 + 255) / 256, 256, 0, stream>>>(h1, a_src1, a_dst1, as1, ad1);
    gat_aggr1_csr<<<(N_NODES + 3) / 4, 256, 0, stream>>>(offs, esrc, as1, ad1, h1, b1, hrelu);

    // ---- layer 2 ----
    gat_gemm<C1, OUT_CH><<<(N_NODES + 63) / 64, 256, 0, stream>>>(hrelu, W2, h2, N_NODES);
    gat_coef2<<<(N_NODES * 64 + 255) / 256, 256, 0, stream>>>(h2, a_src2, a_dst2, as2, ad2);
    gat_aggr2_csr<<<(N_NODES + 3) / 4, 256, 0, stream>>>(offs, esrc, as2, ad2, h2, b2, out);

    (void)in_sizes; (void)n_in; (void)out_size; (void)ws_size;
}

// Round 3
// 358.013 us; speedup vs baseline: 2.4428x; 1.1139x over previous
//
#include <hip/hip_runtime.h>
#include <hip/hip_fp16.h>

#define N_NODES 50000
#define N_EDGES 800000
#define IN_CH   256
#define HID     32
#define HEADS1  4
#define C1      128      // HEADS1*HID
#define OUT_CH  64
#define NEG     0.2f
#define NB      ((N_NODES + 255) / 256)   // 196 scan blocks

// ---- register-tiled fp32 GEMM: C[M,NCOL] = A[M,KTOT] @ B[KTOT,NCOL] ----
// HOUT: write C as fp16 (packed) instead of f32.
template<int KTOT, int NCOL, bool HOUT>
__global__ __launch_bounds__(256) void gat_gemm(const float* __restrict__ A,
                                                const float* __restrict__ B,
                                                void* __restrict__ Cv, int M) {
    constexpr int TN  = NCOL / 16;
    constexpr int LDA = 68;
    constexpr int LDB = NCOL + 4;
    __shared__ float As[32 * LDA];
    __shared__ float Bs[32 * LDB];
    const int tid = threadIdx.x;
    const int ty = tid >> 4, tx = tid & 15;
    const int row0 = blockIdx.x * 64;
    const int r0 = ty * 4;
    const int c0 = tx * TN;
    float acc[4][TN];
#pragma unroll
    for (int r = 0; r < 4; ++r)
#pragma unroll
        for (int j = 0; j < TN; ++j) acc[r][j] = 0.f;

    for (int kk = 0; kk < KTOT; kk += 32) {
#pragma unroll
        for (int p = 0; p < 2; ++p) {
            int r  = (tid >> 3) + p * 32;
            int kb = (tid & 7) * 4;
            float4 v = make_float4(0.f, 0.f, 0.f, 0.f);
            int gr = row0 + r;
            if (gr < M) v = *(const float4*)(A + (size_t)gr * KTOT + kk + kb);
            As[(kb + 0) * LDA + r] = v.x;
            As[(kb + 1) * LDA + r] = v.y;
            As[(kb + 2) * LDA + r] = v.z;
            As[(kb + 3) * LDA + r] = v.w;
        }
        constexpr int NV = NCOL / 4;
        constexpr int NLOAD = 32 * NV / 256;
#pragma unroll
        for (int p = 0; p < NLOAD; ++p) {
            int idx = tid + p * 256;
            int k = idx / NV;
            int j = (idx % NV) * 4;
            *(float4*)(&Bs[k * LDB + j]) = *(const float4*)(B + (size_t)(kk + k) * NCOL + j);
        }
        __syncthreads();
#pragma unroll
        for (int k = 0; k < 32; ++k) {
            float4 a = *(const float4*)(&As[k * LDA + r0]);
            float av[4] = {a.x, a.y, a.z, a.w};
            float bv[TN];
#pragma unroll
            for (int j = 0; j < TN; j += 4) {
                float4 b = *(const float4*)(&Bs[k * LDB + c0 + j]);
                bv[j] = b.x; bv[j + 1] = b.y; bv[j + 2] = b.z; bv[j + 3] = b.w;
            }
#pragma unroll
            for (int r = 0; r < 4; ++r)
#pragma unroll
                for (int j = 0; j < TN; ++j)
                    acc[r][j] = fmaf(av[r], bv[j], acc[r][j]);
        }
        __syncthreads();
    }
#pragma unroll
    for (int r = 0; r < 4; ++r) {
        int gr = row0 + r0 + r;
        if (gr >= M) continue;
        if constexpr (HOUT) {
            __half* C = (__half*)Cv;
            __half tmp[TN];
#pragma unroll
            for (int j = 0; j < TN; ++j) tmp[j] = __float2half(acc[r][j]);
            if constexpr (TN == 8)
                *(float4*)(C + (size_t)gr * NCOL + c0) = *(float4*)tmp;
            else
                *(float2*)(C + (size_t)gr * NCOL + c0) = *(float2*)tmp;
        } else {
            float* C = (float*)Cv;
#pragma unroll
            for (int j = 0; j < TN; j += 4)
                *(float4*)(C + (size_t)gr * NCOL + c0 + j) =
                    make_float4(acc[r][j], acc[r][j + 1], acc[r][j + 2], acc[r][j + 3]);
        }
    }
}

// ================= CSR build =================
__global__ void k_deg(const int* __restrict__ dst, int* __restrict__ deg) {
    int e = blockIdx.x * blockDim.x + threadIdx.x;
    if (e < N_EDGES) atomicAdd(deg + dst[e], 1);
}

__global__ __launch_bounds__(256) void k_scan_block(const int* __restrict__ deg,
                                                    int* __restrict__ offs,
                                                    int* __restrict__ part) {
    __shared__ int s[256];
    int i = blockIdx.x * 256 + threadIdx.x;
    int v = (i < N_NODES) ? deg[i] : 0;
    s[threadIdx.x] = v;
    __syncthreads();
#pragma unroll
    for (int o = 1; o < 256; o <<= 1) {
        int t = (threadIdx.x >= o) ? s[threadIdx.x - o] : 0;
        __syncthreads();
        s[threadIdx.x] += t;
        __syncthreads();
    }
    if (i < N_NODES) offs[i] = s[threadIdx.x] - v;   // exclusive
    if (threadIdx.x == 255) part[blockIdx.x] = s[255];
}

__global__ __launch_bounds__(256) void k_scan_part(int* __restrict__ part) {
    __shared__ int s[256];
    int v = (threadIdx.x < NB) ? part[threadIdx.x] : 0;
    s[threadIdx.x] = v;
    __syncthreads();
#pragma unroll
    for (int o = 1; o < 256; o <<= 1) {
        int t = (threadIdx.x >= o) ? s[threadIdx.x - o] : 0;
        __syncthreads();
        s[threadIdx.x] += t;
        __syncthreads();
    }
    if (threadIdx.x < NB) part[threadIdx.x] = s[threadIdx.x] - v;
}

__global__ void k_scan_add(int* __restrict__ offs, const int* __restrict__ part,
                           int* __restrict__ cur) {
    int i = blockIdx.x * 256 + threadIdx.x;
    if (i < N_NODES) {
        int o = offs[i] + part[blockIdx.x];
        offs[i] = o;
        cur[i] = o;
    }
}

__global__ void k_scatter(const int* __restrict__ src, const int* __restrict__ dst,
                          int* __restrict__ cur, int* __restrict__ esrc) {
    int e = blockIdx.x * blockDim.x + threadIdx.x;
    if (e < N_EDGES) {
        int pos = atomicAdd(cur + dst[e], 1);
        esrc[pos] = src[e];
    }
}

// ================= attention coefficients =================
__global__ void gat_coef1(const __half* __restrict__ h1, const float* __restrict__ a_s,
                          const float* __restrict__ a_d, float* __restrict__ as_n,
                          float* __restrict__ ad_n) {
    int t = blockIdx.x * blockDim.x + threadIdx.x;
    if (t >= N_NODES * HEADS1) return;
    int n = t >> 2, h = t & 3;
    const __half* hp = h1 + (size_t)n * C1 + h * HID;
    const float* ap = a_s + h * HID;
    const float* dp = a_d + h * HID;
    float s = 0.f, d = 0.f;
#pragma unroll
    for (int c = 0; c < HID; ++c) {
        float v = __half2float(hp[c]);
        s = fmaf(v, ap[c], s);
        d = fmaf(v, dp[c], d);
    }
    as_n[t] = s;
    ad_n[t] = d;
}

__global__ void gat_coef2(const __half* __restrict__ h2, const float* __restrict__ a_s,
                          const float* __restrict__ a_d, float* __restrict__ as_n,
                          float* __restrict__ ad_n) {
    int warp = (int)((blockIdx.x * blockDim.x + threadIdx.x) >> 6);
    int lane = threadIdx.x & 63;
    if (warp >= N_NODES) return;
    float v = __half2float(h2[(size_t)warp * 64 + lane]);
    float s = v * a_s[lane];
    float d = v * a_d[lane];
#pragma unroll
    for (int o = 32; o > 0; o >>= 1) {
        s += __shfl_down(s, o);
        d += __shfl_down(d, o);
    }
    if (lane == 0) {
        as_n[warp] = s;
        ad_n[warp] = d;
    }
}

// ================= CSR aggregation: one wave per dst node =================
// Branchless online softmax; fp16 gathers.
__global__ __launch_bounds__(256) void gat_aggr1_csr(const int* __restrict__ offs,
                                                     const int* __restrict__ esrc,
                                                     const float* __restrict__ as1,
                                                     const float* __restrict__ ad1,
                                                     const __half2* __restrict__ h1,
                                                     const float* __restrict__ b1,
                                                     float* __restrict__ hrelu) {
    int n = blockIdx.x * 4 + (threadIdx.x >> 6);
    if (n >= N_NODES) return;
    int lane = threadIdx.x & 63;
    int c = lane * 2;
    int h = c >> 5;
    int base = offs[n];
    int end = (n == N_NODES - 1) ? N_EDGES : offs[n + 1];
    float ad = ad1[n * 4 + h];
    float m = -INFINITY, den = 0.f, a0 = 0.f, a1 = 0.f;
    for (int i = base; i < end; ++i) {
        int s = esrc[i];
        float x = as1[s * 4 + h] + ad;
        x = x > 0.f ? x : NEG * x;
        float nm = fmaxf(m, x);
        float sc = __expf(m - nm);     // exp(-inf)=0 on first edge
        float ex = __expf(x - nm);
        m = nm;
        float2 hv = __half22float2(h1[(size_t)s * 64 + lane]);
        den = fmaf(den, sc, ex);
        a0  = fmaf(a0, sc, hv.x * ex);
        a1  = fmaf(a1, sc, hv.y * ex);
    }
    float inv = 1.f / (den + 1e-16f);
    float v0 = fmaf(a0, inv, b1[c]);
    float v1 = fmaf(a1, inv, b1[c + 1]);
    v0 = v0 > 0.f ? v0 : 0.f;
    v1 = v1 > 0.f ? v1 : 0.f;
    *(float2*)(hrelu + (size_t)n * C1 + c) = make_float2(v0, v1);
}

__global__ __launch_bounds__(256) void gat_aggr2_csr(const int* __restrict__ offs,
                                                     const int* __restrict__ esrc,
                                                     const float* __restrict__ as2,
                                                     const float* __restrict__ ad2,
                                                     const __half* __restrict__ h2,
                                                     const float* __restrict__ b2,
                                                     float* __restrict__ out) {
    int n = blockIdx.x * 4 + (threadIdx.x >> 6);
    if (n >= N_NODES) return;
    int lane = threadIdx.x & 63;
    int base = offs[n];
    int end = (n == N_NODES - 1) ? N_EDGES : offs[n + 1];
    float ad = ad2[n];
    float m = -INFINITY, den = 0.f, a0 = 0.f;
    for (int i = base; i < end; ++i) {
        int s = esrc[i];
        float x = as2[s] + ad;
        x = x > 0.f ? x : NEG * x;
        float nm = fmaxf(m, x);
        float sc = __expf(m - nm);
        float ex = __expf(x - nm);
        m = nm;
        float hv = __half2float(h2[(size_t)s * 64 + lane]);
        den = fmaf(den, sc, ex);
        a0  = fmaf(a0, sc, hv * ex);
    }
    out[(size_t)n * 64 + lane] = a0 / (den + 1e-16f) + b2[lane];
}

extern "C" void kernel_launch(void* const* d_in, const int* in_sizes, int n_in,
                              void* d_out, int out_size, void* d_ws, size_t ws_size,
                              hipStream_t stream) {
    const float* x      = (const float*)d_in[0];
    const int*   ei     = (const int*)d_in[1];
    const float* W1     = (const float*)d_in[2];
    const float* a_src1 = (const float*)d_in[3];
    const float* a_dst1 = (const float*)d_in[4];
    const float* b1     = (const float*)d_in[5];
    const float* W2     = (const float*)d_in[6];
    const float* a_src2 = (const float*)d_in[7];
    const float* a_dst2 = (const float*)d_in[8];
    const float* b2     = (const float*)d_in[9];
    float* out = (float*)d_out;

    const int* src = ei;
    const int* dst = ei + N_EDGES;

    char* w = (char*)d_ws;
    auto carve = [&](size_t bytes) {
        char* p = w;
        w += (bytes + 255) & ~(size_t)255;
        return p;
    };
    __half* h1    = (__half*)carve((size_t)N_NODES * C1 * 2);
    float*  hrelu = (float*)carve((size_t)N_NODES * C1 * 4);
    __half* h2    = (__half*)carve((size_t)N_NODES * 64 * 2);
    float*  as1   = (float*)carve((size_t)N_NODES * 4 * 4);
    float*  ad1   = (float*)carve((size_t)N_NODES * 4 * 4);
    float*  as2   = (float*)carve((size_t)N_NODES * 4);
    float*  ad2   = (float*)carve((size_t)N_NODES * 4);
    int*    deg   = (int*)carve((size_t)N_NODES * 4);
    int*    offs  = (int*)carve((size_t)N_NODES * 4);
    int*    cur   = (int*)carve((size_t)N_NODES * 4);
    int*    part  = (int*)carve((size_t)NB * 4);
    int*    esrc  = (int*)carve((size_t)N_EDGES * 4);

    // ---- CSR build (once, shared by both layers) ----
    hipMemsetAsync(deg, 0, (size_t)N_NODES * 4, stream);
    k_deg<<<(N_EDGES + 255) / 256, 256, 0, stream>>>(dst, deg);
    k_scan_block<<<NB, 256, 0, stream>>>(deg, offs, part);
    k_scan_part<<<1, 256, 0, stream>>>(part);
    k_scan_add<<<NB, 256, 0, stream>>>(offs, part, cur);
    k_scatter<<<(N_EDGES + 255) / 256, 256, 0, stream>>>(src, dst, cur, esrc);

    // ---- layer 1 ----
    gat_gemm<IN_CH, C1, true><<<(N_NODES + 63) / 64, 256, 0, stream>>>(x, W1, h1, N_NODES);
    gat_coef1<<<(N_NODES * 4 + 255) / 256, 256, 0, stream>>>(h1, a_src1, a_dst1, as1, ad1);
    gat_aggr1_csr<<<(N_NODES + 3) / 4, 256, 0, stream>>>(offs, esrc, as1, ad1,
                                                         (const __half2*)h1, b1, hrelu);

    // ---- layer 2 ----
    gat_gemm<C1, OUT_CH, true><<<(N_NODES + 63) / 64, 256, 0, stream>>>(hrelu, W2, h2, N_NODES);
    gat_coef2<<<(N_NODES * 64 + 255) / 256, 256, 0, stream>>>(h2, a_src2, a_dst2, as2, ad2);
    gat_aggr2_csr<<<(N_NODES + 3) / 4, 256, 0, stream>>>(offs, esrc, as2, ad2, h2, b2, out);

    (void)in_sizes; (void)n_in; (void)out_size; (void)ws_size;
}

// Round 4
// 244.631 us; speedup vs baseline: 3.5750x; 1.4635x over previous
//
#include <hip/hip_runtime.h>
#include <hip/hip_fp16.h>

#define N_NODES 50000
#define N_EDGES 800000
#define IN_CH   256
#define HID     32
#define HEADS1  4
#define C1      128      // HEADS1*HID
#define OUT_CH  64
#define NEG     0.2f
#define NB      ((N_NODES + 255) / 256)   // 196 scan blocks
#define NEGINF  (-1e30f)

typedef _Float16 h8 __attribute__((ext_vector_type(8)));
typedef float f32x4 __attribute__((ext_vector_type(4)));

// ================= MFMA GEMM layer1: h1[fp16] = X[f32] @ W1[f32] =================
// block = 4 waves; tile 64 rows x 128 cols; wave w owns rows [w*16, w*16+16).
// LDS rows padded to 40 halves (80B): 16B-aligned chunks, 2-way banks (free).
__global__ __launch_bounds__(256) void gemm1_mfma(const float* __restrict__ X,
                                                  const float* __restrict__ W,
                                                  __half* __restrict__ H) {
    __shared__ _Float16 As[64 * 40];
    __shared__ _Float16 Bt[128 * 40];
    const int tid = threadIdx.x;
    const int w = tid >> 6, lane = tid & 63;
    const int row0 = blockIdx.x * 64;
    const int lr = lane & 15, lk = (lane >> 4) * 8;
    f32x4 acc[8];
#pragma unroll
    for (int n = 0; n < 8; ++n) acc[n] = (f32x4){0.f, 0.f, 0.f, 0.f};

    for (int kk = 0; kk < IN_CH; kk += 32) {
        // stage A: 64x32 f32 -> fp16
        {
            int ar = tid >> 2, aks = (tid & 3) * 8;
            int gr = row0 + ar;
            float4 v0 = make_float4(0.f, 0.f, 0.f, 0.f), v1 = v0;
            if (gr < N_NODES) {
                v0 = *(const float4*)(X + (size_t)gr * IN_CH + kk + aks);
                v1 = *(const float4*)(X + (size_t)gr * IN_CH + kk + aks + 4);
            }
            h8 hv;
            hv[0] = (_Float16)v0.x; hv[1] = (_Float16)v0.y;
            hv[2] = (_Float16)v0.z; hv[3] = (_Float16)v0.w;
            hv[4] = (_Float16)v1.x; hv[5] = (_Float16)v1.y;
            hv[6] = (_Float16)v1.z; hv[7] = (_Float16)v1.w;
            *(h8*)(&As[ar * 40 + aks]) = hv;
        }
        // stage B transposed: W[kk..kk+32)[0..128) -> Bt[col][k]
        {
            int bk = tid >> 3, cs = (tid & 7) * 16;
#pragma unroll
            for (int ii = 0; ii < 16; ii += 4) {
                float4 wv = *(const float4*)(W + (size_t)(kk + bk) * C1 + cs + ii);
                Bt[(cs + ii + 0) * 40 + bk] = (_Float16)wv.x;
                Bt[(cs + ii + 1) * 40 + bk] = (_Float16)wv.y;
                Bt[(cs + ii + 2) * 40 + bk] = (_Float16)wv.z;
                Bt[(cs + ii + 3) * 40 + bk] = (_Float16)wv.w;
            }
        }
        __syncthreads();
        h8 a = *(const h8*)(&As[(w * 16 + lr) * 40 + lk]);
#pragma unroll
        for (int n = 0; n < 8; ++n) {
            h8 b = *(const h8*)(&Bt[(n * 16 + lr) * 40 + lk]);
            acc[n] = __builtin_amdgcn_mfma_f32_16x16x32_f16(a, b, acc[n], 0, 0, 0);
        }
        __syncthreads();
    }
#pragma unroll
    for (int n = 0; n < 8; ++n)
#pragma unroll
        for (int j = 0; j < 4; ++j) {
            int gr = row0 + w * 16 + (lane >> 4) * 4 + j;
            if (gr < N_NODES) H[(size_t)gr * C1 + n * 16 + lr] = __float2half(acc[n][j]);
        }
}

// ================= MFMA GEMM layer2: h2[fp16] = hrelu[fp16] @ W2[f32] =================
// W2 (128x64) staged whole as Bt2[col][k] (64x128, padded to 136).
__global__ __launch_bounds__(256) void gemm2_mfma(const __half* __restrict__ A,
                                                  const float* __restrict__ W,
                                                  __half* __restrict__ H) {
    __shared__ _Float16 Bt[64 * 136];
    const int tid = threadIdx.x;
    const int w = tid >> 6, lane = tid & 63;
    const int row0 = blockIdx.x * 64;
    const int lr = lane & 15, lk = (lane >> 4) * 8;
    {
        int k = tid >> 1, cs = (tid & 1) * 32;
#pragma unroll
        for (int ii = 0; ii < 32; ii += 4) {
            float4 wv = *(const float4*)(W + (size_t)k * OUT_CH + cs + ii);
            Bt[(cs + ii + 0) * 136 + k] = (_Float16)wv.x;
            Bt[(cs + ii + 1) * 136 + k] = (_Float16)wv.y;
            Bt[(cs + ii + 2) * 136 + k] = (_Float16)wv.z;
            Bt[(cs + ii + 3) * 136 + k] = (_Float16)wv.w;
        }
    }
    __syncthreads();
    f32x4 acc[4];
#pragma unroll
    for (int n = 0; n < 4; ++n) acc[n] = (f32x4){0.f, 0.f, 0.f, 0.f};
    int grow = row0 + w * 16 + lr;
    grow = grow < N_NODES ? grow : N_NODES - 1;
    const _Float16* Ah = (const _Float16*)A;
#pragma unroll
    for (int kk = 0; kk < C1; kk += 32) {
        h8 a = *(const h8*)(Ah + (size_t)grow * C1 + kk + lk);
#pragma unroll
        for (int n = 0; n < 4; ++n) {
            h8 b = *(const h8*)(&Bt[(n * 16 + lr) * 136 + kk + lk]);
            acc[n] = __builtin_amdgcn_mfma_f32_16x16x32_f16(a, b, acc[n], 0, 0, 0);
        }
    }
#pragma unroll
    for (int n = 0; n < 4; ++n)
#pragma unroll
        for (int j = 0; j < 4; ++j) {
            int gr = row0 + w * 16 + (lane >> 4) * 4 + j;
            if (gr < N_NODES) H[(size_t)gr * OUT_CH + n * 16 + lr] = __float2half(acc[n][j]);
        }
}

// ================= CSR build =================
__global__ void k_deg(const int* __restrict__ dst, int* __restrict__ deg) {
    int e = blockIdx.x * blockDim.x + threadIdx.x;
    if (e < N_EDGES) atomicAdd(deg + dst[e], 1);
}

__global__ __launch_bounds__(256) void k_scan_block(const int* __restrict__ deg,
                                                    int* __restrict__ offs,
                                                    int* __restrict__ part) {
    __shared__ int s[256];
    int i = blockIdx.x * 256 + threadIdx.x;
    int v = (i < N_NODES) ? deg[i] : 0;
    s[threadIdx.x] = v;
    __syncthreads();
#pragma unroll
    for (int o = 1; o < 256; o <<= 1) {
        int t = (threadIdx.x >= o) ? s[threadIdx.x - o] : 0;
        __syncthreads();
        s[threadIdx.x] += t;
        __syncthreads();
    }
    if (i < N_NODES) offs[i] = s[threadIdx.x] - v;
    if (threadIdx.x == 255) part[blockIdx.x] = s[255];
}

__global__ __launch_bounds__(256) void k_scan_part(int* __restrict__ part) {
    __shared__ int s[256];
    int v = (threadIdx.x < NB) ? part[threadIdx.x] : 0;
    s[threadIdx.x] = v;
    __syncthreads();
#pragma unroll
    for (int o = 1; o < 256; o <<= 1) {
        int t = (threadIdx.x >= o) ? s[threadIdx.x - o] : 0;
        __syncthreads();
        s[threadIdx.x] += t;
        __syncthreads();
    }
    if (threadIdx.x < NB) part[threadIdx.x] = s[threadIdx.x] - v;
}

__global__ void k_scan_add(int* __restrict__ offs, const int* __restrict__ part,
                           int* __restrict__ cur) {
    int i = blockIdx.x * 256 + threadIdx.x;
    if (i < N_NODES) {
        int o = offs[i] + part[blockIdx.x];
        offs[i] = o;
        cur[i] = o;
    }
}

__global__ void k_scatter(const int* __restrict__ src, const int* __restrict__ dst,
                          int* __restrict__ cur, int* __restrict__ esrc) {
    int e = blockIdx.x * blockDim.x + threadIdx.x;
    if (e < N_EDGES) {
        int pos = atomicAdd(cur + dst[e], 1);
        esrc[pos] = src[e];
    }
}

// ================= attention coefficients =================
__global__ void gat_coef1(const __half* __restrict__ h1, const float* __restrict__ a_s,
                          const float* __restrict__ a_d, float* __restrict__ as_n,
                          float* __restrict__ ad_n) {
    int t = blockIdx.x * blockDim.x + threadIdx.x;
    if (t >= N_NODES * HEADS1) return;
    int n = t >> 2, h = t & 3;
    const __half* hp = h1 + (size_t)n * C1 + h * HID;
    const float* ap = a_s + h * HID;
    const float* dp = a_d + h * HID;
    float s = 0.f, d = 0.f;
#pragma unroll
    for (int c = 0; c < HID; ++c) {
        float v = __half2float(hp[c]);
        s = fmaf(v, ap[c], s);
        d = fmaf(v, dp[c], d);
    }
    as_n[t] = s;
    ad_n[t] = d;
}

__global__ void gat_coef2(const __half* __restrict__ h2, const float* __restrict__ a_s,
                          const float* __restrict__ a_d, float* __restrict__ as_n,
                          float* __restrict__ ad_n) {
    int warp = (int)((blockIdx.x * blockDim.x + threadIdx.x) >> 6);
    int lane = threadIdx.x & 63;
    if (warp >= N_NODES) return;
    float v = __half2float(h2[(size_t)warp * 64 + lane]);
    float s = v * a_s[lane];
    float d = v * a_d[lane];
#pragma unroll
    for (int o = 32; o > 0; o >>= 1) {
        s += __shfl_down(s, o);
        d += __shfl_down(d, o);
    }
    if (lane == 0) {
        as_n[warp] = s;
        ad_n[warp] = d;
    }
}

// ================= CSR aggregation: one wave per dst node, 4 edge slots =================
__global__ __launch_bounds__(256) void gat_aggr1_csr(const int* __restrict__ offs,
                                                     const int* __restrict__ esrc,
                                                     const float* __restrict__ as1,
                                                     const float* __restrict__ ad1,
                                                     const __half2* __restrict__ h1,
                                                     const float* __restrict__ b1,
                                                     __half* __restrict__ hrelu) {
    int n = blockIdx.x * 4 + (threadIdx.x >> 6);
    if (n >= N_NODES) return;
    int lane = threadIdx.x & 63;
    int c = lane * 2;
    int h = lane >> 4;
    int base = offs[n];
    int end = (n == N_NODES - 1) ? N_EDGES : offs[n + 1];
    float ad = ad1[n * 4 + h];
    float m[4], den[4], A0[4], A1[4];
#pragma unroll
    for (int u = 0; u < 4; ++u) { m[u] = NEGINF; den[u] = 0.f; A0[u] = 0.f; A1[u] = 0.f; }
    int i = base;
    for (; i + 4 <= end; i += 4) {
#pragma unroll
        for (int u = 0; u < 4; ++u) {
            int s = esrc[i + u];
            float x = as1[s * 4 + h] + ad;
            x = x > 0.f ? x : NEG * x;
            float nm = fmaxf(m[u], x);
            float sc = __expf(m[u] - nm);
            float ex = __expf(x - nm);
            m[u] = nm;
            float2 hv = __half22float2(h1[(size_t)s * 64 + lane]);
            den[u] = fmaf(den[u], sc, ex);
            A0[u] = fmaf(A0[u], sc, hv.x * ex);
            A1[u] = fmaf(A1[u], sc, hv.y * ex);
        }
    }
    for (; i < end; ++i) {
        int s = esrc[i];
        float x = as1[s * 4 + h] + ad;
        x = x > 0.f ? x : NEG * x;
        float nm = fmaxf(m[0], x);
        float sc = __expf(m[0] - nm);
        float ex = __expf(x - nm);
        m[0] = nm;
        float2 hv = __half22float2(h1[(size_t)s * 64 + lane]);
        den[0] = fmaf(den[0], sc, ex);
        A0[0] = fmaf(A0[0], sc, hv.x * ex);
        A1[0] = fmaf(A1[0], sc, hv.y * ex);
    }
    float M = fmaxf(fmaxf(m[0], m[1]), fmaxf(m[2], m[3]));
    float D = 0.f, R0 = 0.f, R1 = 0.f;
#pragma unroll
    for (int u = 0; u < 4; ++u) {
        float f = (m[u] > NEGINF) ? __expf(m[u] - M) : 0.f;
        D = fmaf(den[u], f, D);
        R0 = fmaf(A0[u], f, R0);
        R1 = fmaf(A1[u], f, R1);
    }
    float inv = 1.f / (D + 1e-16f);
    float v0 = fmaf(R0, inv, b1[c]);
    float v1 = fmaf(R1, inv, b1[c + 1]);
    v0 = v0 > 0.f ? v0 : 0.f;
    v1 = v1 > 0.f ? v1 : 0.f;
    __half2 hv2;
    hv2.x = __float2half(v0);
    hv2.y = __float2half(v1);
    *(__half2*)(hrelu + (size_t)n * C1 + c) = hv2;
}

__global__ __launch_bounds__(256) void gat_aggr2_csr(const int* __restrict__ offs,
                                                     const int* __restrict__ esrc,
                                                     const float* __restrict__ as2,
                                                     const float* __restrict__ ad2,
                                                     const __half* __restrict__ h2,
                                                     const float* __restrict__ b2,
                                                     float* __restrict__ out) {
    int n = blockIdx.x * 4 + (threadIdx.x >> 6);
    if (n >= N_NODES) return;
    int lane = threadIdx.x & 63;
    int base = offs[n];
    int end = (n == N_NODES - 1) ? N_EDGES : offs[n + 1];
    float ad = ad2[n];
    float m[4], den[4], A0[4];
#pragma unroll
    for (int u = 0; u < 4; ++u) { m[u] = NEGINF; den[u] = 0.f; A0[u] = 0.f; }
    int i = base;
    for (; i + 4 <= end; i += 4) {
#pragma unroll
        for (int u = 0; u < 4; ++u) {
            int s = esrc[i + u];
            float x = as2[s] + ad;
            x = x > 0.f ? x : NEG * x;
            float nm = fmaxf(m[u], x);
            float sc = __expf(m[u] - nm);
            float ex = __expf(x - nm);
            m[u] = nm;
            float hv = __half2float(h2[(size_t)s * 64 + lane]);
            den[u] = fmaf(den[u], sc, ex);
            A0[u] = fmaf(A0[u], sc, hv * ex);
        }
    }
    for (; i < end; ++i) {
        int s = esrc[i];
        float x = as2[s] + ad;
        x = x > 0.f ? x : NEG * x;
        float nm = fmaxf(m[0], x);
        float sc = __expf(m[0] - nm);
        float ex = __expf(x - nm);
        m[0] = nm;
        float hv = __half2float(h2[(size_t)s * 64 + lane]);
        den[0] = fmaf(den[0], sc, ex);
        A0[0] = fmaf(A0[0], sc, hv * ex);
    }
    float M = fmaxf(fmaxf(m[0], m[1]), fmaxf(m[2], m[3]));
    float D = 0.f, R0 = 0.f;
#pragma unroll
    for (int u = 0; u < 4; ++u) {
        float f = (m[u] > NEGINF) ? __expf(m[u] - M) : 0.f;
        D = fmaf(den[u], f, D);
        R0 = fmaf(A0[u], f, R0);
    }
    out[(size_t)n * 64 + lane] = R0 / (D + 1e-16f) + b2[lane];
}

extern "C" void kernel_launch(void* const* d_in, const int* in_sizes, int n_in,
                              void* d_out, int out_size, void* d_ws, size_t ws_size,
                              hipStream_t stream) {
    const float* x      = (const float*)d_in[0];
    const int*   ei     = (const int*)d_in[1];
    const float* W1     = (const float*)d_in[2];
    const float* a_src1 = (const float*)d_in[3];
    const float* a_dst1 = (const float*)d_in[4];
    const float* b1     = (const float*)d_in[5];
    const float* W2     = (const float*)d_in[6];
    const float* a_src2 = (const float*)d_in[7];
    const float* a_dst2 = (const float*)d_in[8];
    const float* b2     = (const float*)d_in[9];
    float* out = (float*)d_out;

    const int* src = ei;
    const int* dst = ei + N_EDGES;

    char* w = (char*)d_ws;
    auto carve = [&](size_t bytes) {
        char* p = w;
        w += (bytes + 255) & ~(size_t)255;
        return p;
    };
    __half* h1    = (__half*)carve((size_t)N_NODES * C1 * 2);
    __half* hrelu = (__half*)carve((size_t)N_NODES * C1 * 2);
    __half* h2    = (__half*)carve((size_t)N_NODES * 64 * 2);
    float*  as1   = (float*)carve((size_t)N_NODES * 4 * 4);
    float*  ad1   = (float*)carve((size_t)N_NODES * 4 * 4);
    float*  as2   = (float*)carve((size_t)N_NODES * 4);
    float*  ad2   = (float*)carve((size_t)N_NODES * 4);
    int*    deg   = (int*)carve((size_t)N_NODES * 4);
    int*    offs  = (int*)carve((size_t)N_NODES * 4);
    int*    cur   = (int*)carve((size_t)N_NODES * 4);
    int*    part  = (int*)carve((size_t)NB * 4);
    int*    esrc  = (int*)carve((size_t)N_EDGES * 4);

    // ---- CSR build (once, shared by both layers) ----
    hipMemsetAsync(deg, 0, (size_t)N_NODES * 4, stream);
    k_deg<<<(N_EDGES + 255) / 256, 256, 0, stream>>>(dst, deg);
    k_scan_block<<<NB, 256, 0, stream>>>(deg, offs, part);
    k_scan_part<<<1, 256, 0, stream>>>(part);
    k_scan_add<<<NB, 256, 0, stream>>>(offs, part, cur);
    k_scatter<<<(N_EDGES + 255) / 256, 256, 0, stream>>>(src, dst, cur, esrc);

    // ---- layer 1 ----
    gemm1_mfma<<<(N_NODES + 63) / 64, 256, 0, stream>>>(x, W1, h1);
    gat_coef1<<<(N_NODES * 4 + 255) / 256, 256, 0, stream>>>(h1, a_src1, a_dst1, as1, ad1);
    gat_aggr1_csr<<<(N_NODES + 3) / 4, 256, 0, stream>>>(offs, esrc, as1, ad1,
                                                         (const __half2*)h1, b1, hrelu);

    // ---- layer 2 ----
    gemm2_mfma<<<(N_NODES + 63) / 64, 256, 0, stream>>>(hrelu, W2, h2);
    gat_coef2<<<(N_NODES * 64 + 255) / 256, 256, 0, stream>>>(h2, a_src2, a_dst2, as2, ad2);
    gat_aggr2_csr<<<(N_NODES + 3) / 4, 256, 0, stream>>>(offs, esrc, as2, ad2, h2, b2, out);

    (void)in_sizes; (void)n_in; (void)out_size; (void)ws_size;
}